// Round 10
// baseline (886.687 us; speedup 1.0000x reference)
//
#include <hip/hip_runtime.h>

// y[b, n*DOUT+o] = sum_i x[b,n,i] * W[n,i,o] + bias[n,o]
// B=2048, N=64, DIN=512, DOUT=512, fp32 in/out, bf16 MFMA (fp32 accum).
// R10: W-RESIDENT, ZERO-BARRIER main loop. Block = (node, 64 cols): W panel
// 512x64 bf16 = 64KB LDS loaded once; 16 waves each stream their own x rows
// global->reg->cvt->MFMA with no inter-wave sync. Grid 512 (64 nodes x 8
// colblocks), node->XCD affinity so a node's colblocks share x via L2.

#define NN 64
#define DIN 512
#define DOUT 512
#define COLS 64
#define ROWSTRIDE (NN * DIN)
#define OUTSTRIDE (NN * DOUT)

typedef __bf16 bf16x8 __attribute__((ext_vector_type(8)));
typedef float f32x4 __attribute__((ext_vector_type(4)));

__device__ __forceinline__ unsigned short f2bf(float f) {
    return __builtin_bit_cast(unsigned short, (__bf16)f);  // RNE
}
__device__ __forceinline__ unsigned int f2bf2(float a, float b) {
    return (unsigned int)f2bf(a) | ((unsigned int)f2bf(b) << 16);
}

// ---- pre-pass: Wt[n][o][i] = bf16(W[n][i][o]) ----
__global__ void wt_transpose_kernel(const float* __restrict__ W,
                                    unsigned short* __restrict__ Wt) {
    __shared__ float tile[32][33];
    const int n  = blockIdx.z;
    const int i0 = blockIdx.x * 32;
    const int o0 = blockIdx.y * 32;
    const float* Wn = W + (size_t)n * DIN * DOUT;
    unsigned short* Wtn = Wt + (size_t)n * DIN * DOUT;
    const int tx = threadIdx.x, ty = threadIdx.y;
#pragma unroll
    for (int q = 0; q < 4; ++q)
        tile[ty + q * 8][tx] = Wn[(size_t)(i0 + ty + q * 8) * DOUT + (o0 + tx)];
    __syncthreads();
#pragma unroll
    for (int q = 0; q < 4; ++q)
        Wtn[(size_t)(o0 + ty + q * 8) * DIN + (i0 + tx)] = f2bf(tile[tx][ty + q * 8]);
}

// ---- main GEMM: block = (node, 64-col panel), W-resident in LDS ----
__global__ __launch_bounds__(1024) void node_gemm_kernel(
    const float* __restrict__ X, const unsigned short* __restrict__ Wt,
    const float* __restrict__ Bias, float* __restrict__ Out) {
    // Wl[col][kslot ^ (col&7)]: 64 cols x 64 slots of 16B (8 bf16 K-elems)
    __shared__ uint4 Wl[COLS * 64];   // 64 KB

    // 512 WGs: node n -> XCD n&7; a node's 8 colblocks contiguous per XCD.
    const int bid  = blockIdx.x;
    const int xcd  = bid & 7;
    const int seq  = bid >> 3;             // 0..63
    const int node = xcd + (seq >> 3) * 8; // 0..63
    const int bcol = (seq & 7) * COLS;

    const int tid  = threadIdx.x;
    const int lane = tid & 63;
    const int w    = tid >> 6;             // 0..15: row-group (64 rows each)

    // ---- one-time LDS fill (coalesced 16B reads from Wt, swizzled writes)
    const unsigned short* Wb = Wt + (size_t)node * DIN * DOUT + (size_t)bcol * DIN;
#pragma unroll
    for (int i = 0; i < 4; ++i) {
        const int s   = i * 1024 + tid;    // 0..4095
        const int col = s >> 6;
        const int ks  = s & 63;
        Wl[col * 64 + (ks ^ (col & 7))] =
            *reinterpret_cast<const uint4*>(Wb + (size_t)col * DIN + ks * 8);
    }
    __syncthreads();   // the ONLY barrier

    const int frow = lane & 15;
    const int q    = lane >> 4;            // 0..3
    const int cxor = frow & 7;             // (n*16+frow)&7 == frow&7

    // per-lane x base: row = w*64 + frow (+ m*16 + c*1024), k = q*8 (+ kt*32)
    const float* Xbase = X + (size_t)(w * 64 + frow) * ROWSTRIDE + node * DIN + q * 8;

    int bslot[4];
#pragma unroll
    for (int n = 0; n < 4; ++n) bslot[n] = (n * 16 + frow) * 64;

    const float* bn = Bias + node * DOUT + bcol;

    for (int c = 0; c < 2; ++c) {          // two 1024-row passes
        f32x4 acc[4][4] = {};
        const float* Xc = Xbase + (size_t)c * 1024 * ROWSTRIDE;

#pragma unroll
        for (int kt = 0; kt < 16; ++kt) {
            bf16x8 bq[4];
#pragma unroll
            for (int n = 0; n < 4; ++n) {
                const uint4 v = Wl[bslot[n] + ((kt * 4 + q) ^ cxor)];
                bq[n] = __builtin_bit_cast(bf16x8, v);
            }
            bf16x8 af[4];
#pragma unroll
            for (int m = 0; m < 4; ++m) {
                const float* p = Xc + (size_t)m * 16 * ROWSTRIDE + kt * 32;
                const float4 lo = *reinterpret_cast<const float4*>(p);
                const float4 hi = *reinterpret_cast<const float4*>(p + 4);
                uint4 pk;
                pk.x = f2bf2(lo.x, lo.y);
                pk.y = f2bf2(lo.z, lo.w);
                pk.z = f2bf2(hi.x, hi.y);
                pk.w = f2bf2(hi.z, hi.w);
                af[m] = __builtin_bit_cast(bf16x8, pk);
            }
#pragma unroll
            for (int m = 0; m < 4; ++m)
#pragma unroll
                for (int n = 0; n < 4; ++n)
                    acc[m][n] = __builtin_amdgcn_mfma_f32_16x16x32_bf16(af[m], bq[n], acc[m][n], 0, 0, 0);
        }

        // epilogue: D mapping col = lane&15, row = (lane>>4)*4 + j
        const int rowbase = c * 1024 + w * 64;
        float* outb = Out + (size_t)rowbase * OUTSTRIDE + node * DOUT + bcol;
#pragma unroll
        for (int n = 0; n < 4; ++n) {
            const int col = n * 16 + frow;
            const float bias = bn[col];
#pragma unroll
            for (int m = 0; m < 4; ++m) {
                const int r0 = m * 16 + q * 4;
#pragma unroll
                for (int j = 0; j < 4; ++j)
                    outb[(size_t)(r0 + j) * OUTSTRIDE + col] = acc[m][n][j] + bias;
            }
        }
    }
}

extern "C" void kernel_launch(void* const* d_in, const int* in_sizes, int n_in,
                              void* d_out, int out_size, void* d_ws, size_t ws_size,
                              hipStream_t stream) {
    const float* x = (const float*)d_in[0];      // [2048, 64, 512]
    const float* W = (const float*)d_in[1];      // [64, 512, 512]
    const float* b = (const float*)d_in[2];      // [64, 512]
    float* out = (float*)d_out;                  // [2048, 64*512]
    unsigned short* Wt = (unsigned short*)d_ws;  // bf16 [64][512][512] = 33.5 MB

    wt_transpose_kernel<<<dim3(DIN / 32, DOUT / 32, NN), dim3(32, 8), 0, stream>>>(W, Wt);
    node_gemm_kernel<<<dim3(512), dim3(1024), 0, stream>>>(x, Wt, b, out);
}

// Round 11
// 203.105 us; speedup vs baseline: 4.3656x; 4.3656x over previous
//
#include <hip/hip_runtime.h>

// y[b, n*DOUT+o] = sum_i x[b,n,i] * W[n,i,o] + bias[n,o]
// B=2048, N=64, DIN=512, DOUT=512, fp32 in/out, bf16 MFMA (fp32 accum).
// R11 = R5 (190us, clean counters) with the end-of-step vmcnt(0) drain
// replaced by a counted-wait ledger. Pure reorder: same registers, same LDS,
// same dataflow. Per iter: loadA(kt+1); stageB(kt+1); waitv(4) [drain B(kt)];
// compute(kt); waitv(2) [drain A(kt+1), B(kt+1) stays in flight]; storeA;
// lgkm(0); s_barrier. One barrier/step, no full drain until the tail.

#define NN 64
#define DIN 512
#define DOUT 512
#define BM 128
#define BN 256
#define BK 32
#define KSTEPS (DIN / BK)         // 16
#define ROWSTRIDE (NN * DIN)
#define OUTSTRIDE (NN * DOUT)

typedef __bf16 bf16x8 __attribute__((ext_vector_type(8)));
typedef float f32x4 __attribute__((ext_vector_type(4)));

__device__ __forceinline__ unsigned short f2bf(float f) {
    return __builtin_bit_cast(unsigned short, (__bf16)f);  // RNE
}
__device__ __forceinline__ unsigned int f2bf2(float a, float b) {
    return (unsigned int)f2bf(a) | ((unsigned int)f2bf(b) << 16);
}

typedef const __attribute__((address_space(1))) unsigned int* gas1_t;
typedef __attribute__((address_space(3))) unsigned int* las3_t;
__device__ __forceinline__ void gload_lds16(const void* g, void* l) {
    __builtin_amdgcn_global_load_lds((gas1_t)g, (las3_t)l, 16, 0, 0);
}

#define WAITV(n)  asm volatile("s_waitcnt vmcnt(" #n ")" ::: "memory")
#define WAITLGKM  asm volatile("s_waitcnt lgkmcnt(0)" ::: "memory")

// ---- pre-pass: Wt[n][o][i] = bf16(W[n][i][o]) ----
__global__ void wt_transpose_kernel(const float* __restrict__ W,
                                    unsigned short* __restrict__ Wt) {
    __shared__ float tile[32][33];
    const int n  = blockIdx.z;
    const int i0 = blockIdx.x * 32;
    const int o0 = blockIdx.y * 32;
    const float* Wn = W + (size_t)n * DIN * DOUT;
    unsigned short* Wtn = Wt + (size_t)n * DIN * DOUT;
    const int tx = threadIdx.x, ty = threadIdx.y;
#pragma unroll
    for (int q = 0; q < 4; ++q)
        tile[ty + q * 8][tx] = Wn[(size_t)(i0 + ty + q * 8) * DOUT + (o0 + tx)];
    __syncthreads();
#pragma unroll
    for (int q = 0; q < 4; ++q)
        Wtn[(size_t)(o0 + ty + q * 8) * DIN + (i0 + tx)] = f2bf(tile[tx][ty + q * 8]);
}

// ---- main GEMM ----
__global__ __launch_bounds__(512, 4) void node_gemm_kernel(
    const float* __restrict__ X, const unsigned short* __restrict__ Wt,
    const float* __restrict__ Bias, float* __restrict__ Out) {
    // layout: [row][4 slots of 8 shorts], slot' = slot ^ ((row>>1)&3)
    __shared__ unsigned short As[2][BM * BK];   // 2 x 8 KB
    __shared__ unsigned short Bs[2][BN * BK];   // 2 x 16 KB

    // 2048 WGs, bijective XCD swizzle (2048 % 8 == 0)
    const int bid = blockIdx.x;
    const int swz = (bid & 7) * 256 + (bid >> 3);
    const int node  = swz >> 5;
    const int rem   = swz & 31;
    const int mtile = rem >> 1;
    const int ntile = rem & 1;
    const int brow = mtile * BM;
    const int bcol = ntile * BN;

    const int tid  = threadIdx.x;
    const int lane = tid & 63;
    const int w    = tid >> 6;        // 0..7
    const int wm   = w >> 2;          // 0..1
    const int wn   = w & 3;           // 0..3

    const float* Xb = X + (size_t)brow * ROWSTRIDE + node * DIN;
    const unsigned short* Wb = Wt + (size_t)node * DIN * DOUT + (size_t)bcol * DIN;

    // A staging: thread t -> row t>>2 (0..127), slot t&3 (8 floats)
    const int a_r  = tid >> 2;
    const int a_s  = tid & 3;
    const int a_sw = a_s ^ ((a_r >> 1) & 3);
    const float* a_src = Xb + (size_t)a_r * ROWSTRIDE + a_s * 8;
    const int a_dst = a_r * BK + a_sw * 8;   // shorts

    // B staging via gload_lds: inst i = q*8+w covers B-cols 16i..16i+15
    const unsigned short* b_src[2];
    int b_dst[2];
#pragma unroll
    for (int q = 0; q < 2; ++q) {
        const int i = q * 8 + w;
        const int c = i * 16 + (lane >> 2);
        const int s = lane & 3;
        const int gs = s ^ ((c >> 1) & 3);       // inverse slot swizzle on source
        b_src[q] = Wb + (size_t)c * DIN + gs * 8;
        b_dst[q] = i * 512;                      // shorts (1KB per inst)
    }

    // fragment read offsets (swizzled K-slot)
    const int arow = lane & 15;
    const int akk  = lane >> 4;
    const int kswz = akk ^ ((arow >> 1) & 3);
    const int afrag = (wm * 64 + arow) * BK + kswz * 8;
    const int bfrag = (wn * 64 + arow) * BK + kswz * 8;

    f32x4 acc[4][4] = {};
    float4 av0, av1;   // single A prefetch set (same footprint as R5)

    auto stageB = [&](int buf, int kt) {
#pragma unroll
        for (int q = 0; q < 2; ++q)
            gload_lds16(b_src[q] + kt * BK, &Bs[buf][b_dst[q]]);
    };
    auto loadA = [&](int kt) {
        const float* p = a_src + kt * BK;
        av0 = *reinterpret_cast<const float4*>(p);
        av1 = *reinterpret_cast<const float4*>(p + 4);
    };
    auto storeA = [&](int buf) {
        uint4 pk;
        pk.x = f2bf2(av0.x, av0.y);
        pk.y = f2bf2(av0.z, av0.w);
        pk.z = f2bf2(av1.x, av1.y);
        pk.w = f2bf2(av1.z, av1.w);
        *reinterpret_cast<uint4*>(&As[buf][a_dst]) = pk;
    };
    auto compute = [&](int buf) {
        bf16x8 af[4], bq[4];
#pragma unroll
        for (int m = 0; m < 4; ++m)
            af[m] = *reinterpret_cast<const bf16x8*>(&As[buf][afrag + m * 16 * BK]);
#pragma unroll
        for (int n = 0; n < 4; ++n)
            bq[n] = *reinterpret_cast<const bf16x8*>(&Bs[buf][bfrag + n * 16 * BK]);
        __builtin_amdgcn_s_setprio(1);
#pragma unroll
        for (int m = 0; m < 4; ++m)
#pragma unroll
            for (int n = 0; n < 4; ++n)
                acc[m][n] = __builtin_amdgcn_mfma_f32_16x16x32_bf16(af[m], bq[n], acc[m][n], 0, 0, 0);
        __builtin_amdgcn_s_setprio(0);
    };

    // ---- prologue: queue [A(0) 2, B(0) 2]; drain A(0), leave B(0) flying.
    loadA(0);
    stageB(0, 0);
    WAITV(2);            // A(0) landed (oldest 2); B(0) still in flight
    storeA(0);
    WAITLGKM;
    __builtin_amdgcn_s_barrier();

    // ---- main loop. Steady-state queue at iter top: [B(kt) 2].
#pragma unroll
    for (int kt = 0; kt < KSTEPS; ++kt) {
        const int buf = kt & 1;
        if (kt + 1 < KSTEPS) {
            loadA(kt + 1);                 // queue: B(kt)2, A2
            stageB(buf ^ 1, kt + 1);       // queue: B(kt)2, A2, B(kt+1)2
            WAITV(4);                      // drain B(kt); A+B(kt+1) keep flying
        } else {
            WAITV(0);                      // tail: only B(15) outstanding
        }
        compute(buf);
        if (kt + 1 < KSTEPS) {
            WAITV(2);                      // drain A(kt+1); B(kt+1) keeps flying
            storeA(buf ^ 1);
            WAITLGKM;                      // publish ds_write before barrier
            __builtin_amdgcn_s_barrier();
        }
    }

    // ---- epilogue: D mapping col = lane&15, row = (lane>>4)*4 + j
    const float* bn = Bias + node * DOUT + bcol;
    float* outb = Out + (size_t)brow * OUTSTRIDE + node * DOUT + bcol;
#pragma unroll
    for (int n = 0; n < 4; ++n) {
        const int col = wn * 64 + n * 16 + arow;
        const float bias = bn[col];
#pragma unroll
        for (int m = 0; m < 4; ++m) {
            const int r0 = wm * 64 + m * 16 + akk * 4;
#pragma unroll
            for (int j = 0; j < 4; ++j)
                outb[(size_t)(r0 + j) * OUTSTRIDE + col] = acc[m][n][j] + bias;
        }
    }
}

extern "C" void kernel_launch(void* const* d_in, const int* in_sizes, int n_in,
                              void* d_out, int out_size, void* d_ws, size_t ws_size,
                              hipStream_t stream) {
    const float* x = (const float*)d_in[0];      // [2048, 64, 512]
    const float* W = (const float*)d_in[1];      // [64, 512, 512]
    const float* b = (const float*)d_in[2];      // [64, 512]
    float* out = (float*)d_out;                  // [2048, 64*512]
    unsigned short* Wt = (unsigned short*)d_ws;  // bf16 [64][512][512] = 33.5 MB

    wt_transpose_kernel<<<dim3(DIN / 32, DOUT / 32, NN), dim3(32, 8), 0, stream>>>(W, Wt);
    node_gemm_kernel<<<dim3(2048), dim3(512), 0, stream>>>(x, Wt, b, out);
}